// Round 11
// baseline (66.374 us; speedup 1.0000x reference)
//
#include <hip/hip_runtime.h>

namespace {

constexpr int B = 8, C = 4, K = 5;
constexpr int HW = 512 * 1024;  // pixels per (b,c) plane
constexpr int NG = HW / 4;      // float4 groups per plane (131072)
constexpr int NT = 256;         // threads per block
constexpr int GPB = 256;        // blocks per batch
constexpr int NBLK = GPB * B;   // 2048 blocks = 8/CU (VGPR<=64 guaranteed)
constexpr int SGRP = GPB * NT;  // 65536 = NG/2 -> exactly 2 groups/thread
constexpr int SS = 4;           // atomic sub-slots (shorter RMW chains)
constexpr int LINE = 32;        // floats per 128B line
constexpr float DV = 0.5f;      // DELTA_V
constexpr float DD = 3.0f;      // DELTA_D
constexpr double FXST = 16777216.0;       // 2^24 stats fixed-point scale
constexpr double FXSV = 1099511627776.0;  // 2^40 var fixed-point scale

using u64 = unsigned long long;

// ws float layout; every RMW slot owns a 128B line; ALL zeroed by
// zero_kernel (node 0) each call -> init-value independent. All cross-block
// sums are INTEGER fixed-point (associative -> deterministic, and
// bit-identical between the fused and fallback paths).
constexpr int ST_OFF = 0;                               // [B*25*SS] u64
constexpr int IACC_OFF = ST_OFF + B * 25 * SS * LINE;   // [B*SS] u64
constexpr int C1S_OFF = IACC_OFF + B * SS * LINE;       // [B*SS] u32
constexpr int C1M_OFF = C1S_OFF + B * SS * LINE;        // [B] u32
constexpr int C2S_OFF = C1M_OFF + B * LINE;             // [B*SS] u32
constexpr int GC_OFF = C2S_OFF + B * SS * LINE;         // 1 u32
constexpr int WS_FLOATS = GC_OFF + LINE;                // 28960 (~116 KB)

__device__ __forceinline__ float wave_reduce(float v) {
#pragma unroll
  for (int m = 32; m; m >>= 1) v += __shfl_xor(v, m, 64);
  return v;
}

__device__ __forceinline__ u64 aload64(const float* p) {
  return __hip_atomic_load(reinterpret_cast<const u64*>(p), __ATOMIC_RELAXED,
                           __HIP_MEMORY_SCOPE_AGENT);
}

__global__ void zero_kernel(float* __restrict__ ws) {
  const int i = blockIdx.x * blockDim.x + threadIdx.x;
  if (i < WS_FLOATS) ws[i] = 0.f;
}

// ---- Phase 1: label counts + channel sums -> fixed-point stat slots ----
__device__ __forceinline__ void phase1_work(const float* __restrict__ emb,
                                            const int* __restrict__ lab,
                                            float* __restrict__ ws, int b,
                                            int bxl, int tid,
                                            float red[4][25]) {
  const int wv = tid >> 6, ln = tid & 63;
  const float4* __restrict__ ep =
      reinterpret_cast<const float4*>(emb + (size_t)b * C * HW);
  const int4* __restrict__ lp =
      reinterpret_cast<const int4*>(lab + (size_t)b * HW);
  const int g0 = bxl * NT + tid, g1 = g0 + SGRP;

  const int4 la = lp[g0], lb2 = lp[g1];
  const float4 a0 = ep[g0], a1 = ep[NG + g0], a2 = ep[2 * NG + g0],
               a3 = ep[3 * NG + g0];
  const float4 b0 = ep[g1], b1 = ep[NG + g1], b2 = ep[2 * NG + g1],
               b3 = ep[3 * NG + g1];

  float acc[25];  // [k][{c0..c3,cnt}] flat, compile-time indexed only
#pragma unroll
  for (int i = 0; i < 25; i++) acc[i] = 0.f;
  auto accum = [&](int l, float v0, float v1, float v2, float v3) {
#pragma unroll
    for (int k = 0; k < K; k++) {  // branchless predicated accumulate
      const float m = (l == k + 1) ? 1.f : 0.f;
      acc[k * 5 + 0] = fmaf(m, v0, acc[k * 5 + 0]);
      acc[k * 5 + 1] = fmaf(m, v1, acc[k * 5 + 1]);
      acc[k * 5 + 2] = fmaf(m, v2, acc[k * 5 + 2]);
      acc[k * 5 + 3] = fmaf(m, v3, acc[k * 5 + 3]);
      acc[k * 5 + 4] += m;
    }
  };
  accum(la.x, a0.x, a1.x, a2.x, a3.x);
  accum(la.y, a0.y, a1.y, a2.y, a3.y);
  accum(la.z, a0.z, a1.z, a2.z, a3.z);
  accum(la.w, a0.w, a1.w, a2.w, a3.w);
  accum(lb2.x, b0.x, b1.x, b2.x, b3.x);
  accum(lb2.y, b0.y, b1.y, b2.y, b3.y);
  accum(lb2.z, b0.z, b1.z, b2.z, b3.z);
  accum(lb2.w, b0.w, b1.w, b2.w, b3.w);

#pragma unroll
  for (int i = 0; i < 25; i++) {
    const float v = wave_reduce(acc[i]);
    if (ln == 0) red[wv][i] = v;
  }
  __syncthreads();
  if (tid < 25) {  // publish: integer atomicAdd, 64-long chain per sub-slot
    const float t =
        (red[0][tid] + red[1][tid]) + (red[2][tid] + red[3][tid]);
    const long long q = (long long)((double)t * FXST);
    atomicAdd(reinterpret_cast<u64*>(
                  ws + ST_OFF +
                  ((size_t)(b * 25 + tid) * SS + (bxl & (SS - 1))) * LINE),
              (u64)q);
  }
}

// ---- Phase 2: read stat slots -> means + counts in LDS ----
__device__ __forceinline__ void phase2_stats(const float* __restrict__ ws,
                                             int b, int tid, float sm[K][C],
                                             float scnt[K], float stot[25]) {
  if (tid < 25) {
    long long s = 0;
#pragma unroll
    for (int j = 0; j < SS; j++)
      s += (long long)aload64(ws + ST_OFF +
                              ((size_t)(b * 25 + tid) * SS + j) * LINE);
    stot[tid] = (float)((double)s / FXST);
  }
  __syncthreads();
  if (tid < K * C) {
    const int k = tid / C, c = tid % C;
    sm[k][c] = stot[k * 5 + c] / stot[k * 5 + 4];
  }
  if (tid < K) scnt[tid] = stot[tid * 5 + 4];
  __syncthreads();
}

// ---- Phase 3: masked relu(||e-mean||-DV)^2 -> per-batch iacc sub-slot ----
__device__ __forceinline__ void phase3_work(const float* __restrict__ emb,
                                            const int* __restrict__ lab,
                                            float* __restrict__ ws, int b,
                                            int bxl, int tid,
                                            const float sm[K][C],
                                            const float scnt[K],
                                            float red2[4][K]) {
  const int wv = tid >> 6, ln = tid & 63;
  const float4* __restrict__ ep =
      reinterpret_cast<const float4*>(emb + (size_t)b * C * HW);
  const int4* __restrict__ lp =
      reinterpret_cast<const int4*>(lab + (size_t)b * HW);
  const int g0 = bxl * NT + tid, g1 = g0 + SGRP;

  const int4 la = lp[g0], lb2 = lp[g1];
  const float4 a0 = ep[g0], a1 = ep[NG + g0], a2 = ep[2 * NG + g0],
               a3 = ep[3 * NG + g0];
  const float4 b0 = ep[g1], b1 = ep[NG + g1], b2 = ep[2 * NG + g1],
               b3 = ep[3 * NG + g1];

  float vacc[K] = {0.f, 0.f, 0.f, 0.f, 0.f};
  auto accum = [&](int l, float v0, float v1, float v2, float v3) {
    const int kk = (l > 0) ? (l - 1) : 0;  // safe index; l==0 masked below
    const float d0 = v0 - sm[kk][0];
    const float d1 = v1 - sm[kk][1];
    const float d2 = v2 - sm[kk][2];
    const float d3 = v3 - sm[kk][3];
    const float t =
        fmaxf(sqrtf(d0 * d0 + d1 * d1 + d2 * d2 + d3 * d3) - DV, 0.f);
    const float t2 = t * t;
#pragma unroll
    for (int k = 0; k < K; k++) vacc[k] += (l == k + 1) ? t2 : 0.f;
  };
  accum(la.x, a0.x, a1.x, a2.x, a3.x);
  accum(la.y, a0.y, a1.y, a2.y, a3.y);
  accum(la.z, a0.z, a1.z, a2.z, a3.z);
  accum(la.w, a0.w, a1.w, a2.w, a3.w);
  accum(lb2.x, b0.x, b1.x, b2.x, b3.x);
  accum(lb2.y, b0.y, b1.y, b2.y, b3.y);
  accum(lb2.z, b0.z, b1.z, b2.z, b3.z);
  accum(lb2.w, b0.w, b1.w, b2.w, b3.w);

#pragma unroll
  for (int i = 0; i < K; i++) {
    const float v = wave_reduce(vacc[i]);
    if (ln == 0) red2[wv][i] = v;
  }
  __syncthreads();
  if (tid == 0) {
    float sblk = 0.f;
#pragma unroll
    for (int k = 0; k < K; k++) {
      sblk += ((red2[0][k] + red2[1][k]) + (red2[2][k] + red2[3][k])) /
              scnt[k];
    }
    const u64 fx = (u64)(long long)((double)sblk * FXSV);
    atomicAdd(reinterpret_cast<u64*>(
                  ws + IACC_OFF + ((size_t)b * SS + (bxl & (SS - 1))) * LINE),
              fx);
  }
}

// ---- Finalize: pairwise-centroid term + faithful running-division scan ----
__device__ __forceinline__ void finalize_work(const float* __restrict__ ws,
                                              float* __restrict__ out, int tid,
                                              float stF[B * 25], float sb[B]) {
  if (tid < B * 25) {
    long long s = 0;
#pragma unroll
    for (int j = 0; j < SS; j++)
      s += (long long)aload64(ws + ST_OFF + ((size_t)tid * SS + j) * LINE);
    stF[tid] = (float)((double)s / FXST);
  }
  if (tid < B) {
    long long s = 0;
#pragma unroll
    for (int j = 0; j < SS; j++)
      s += (long long)aload64(ws + IACC_OFF + ((size_t)tid * SS + j) * LINE);
    sb[tid] = (float)((double)s / FXSV);
  }
  __syncthreads();
  if (tid != 0) return;

  float v = 0.f, d = 0.f;
  for (int bb = 0; bb < B; bb++) {
    float m[K][C];
#pragma unroll
    for (int k = 0; k < K; k++) {
      const float cnt = stF[bb * 25 + k * 5 + 4];
#pragma unroll
      for (int c = 0; c < C; c++) m[k][c] = stF[bb * 25 + k * 5 + c] / cnt;
    }
    float p = 0.f;
#pragma unroll
    for (int i = 0; i < K; i++) {
#pragma unroll
      for (int j = 0; j < K; j++) {
        if (i == j) continue;  // diagonal term is exactly 0
        float dd = 0.f;
#pragma unroll
        for (int c = 0; c < C; c++) {
          const float t = m[i][c] - m[j][c];
          dd += t * t;
        }
        const float r = fmaxf(DD - sqrtf(dd), 0.f);
        p += r * r;
      }
    }
    v = (v + sb[bb]) / (float)K;
    d = (d + p) / (float)(2 * K * (K - 1));
  }
  out[0] = v / (float)B;
  out[1] = d / (float)B;
}

// ---- Fused single-kernel path (requires 8 blocks/CU co-residency) ----
__global__ __launch_bounds__(NT, 8) void fused_kernel(
    const float* __restrict__ emb, const int* __restrict__ lab,
    float* __restrict__ ws, float* __restrict__ out) {
  const int b = blockIdx.x >> 8, bxl = blockIdx.x & (GPB - 1);
  const int tid = threadIdx.x;
  __shared__ float red[4][25];
  __shared__ float stot[25];
  __shared__ float sm[K][C];
  __shared__ float scnt[K];
  __shared__ float red2[4][K];
  __shared__ unsigned lastFlag;

  phase1_work(emb, lab, ws, b, bxl, tid, red);

  // per-batch barrier: two-level arrival (64-chains) + relaxed-load spin
  if (tid == 0) {
    asm volatile("s_waitcnt vmcnt(0)" ::: "memory");  // drain stat publishes
    unsigned* c1s = reinterpret_cast<unsigned*>(
        ws + C1S_OFF + ((size_t)b * SS + (bxl & (SS - 1))) * LINE);
    const unsigned olds = atomicAdd(c1s, 1u);
    if (olds == (unsigned)(GPB / SS - 1)) {  // sub-group finisher
      asm volatile("s_waitcnt vmcnt(0)" ::: "memory");
      atomicAdd(reinterpret_cast<unsigned*>(ws + C1M_OFF + (size_t)b * LINE),
                1u);
    }
    const unsigned* c1m =
        reinterpret_cast<const unsigned*>(ws + C1M_OFF + (size_t)b * LINE);
    while (__hip_atomic_load(c1m, __ATOMIC_RELAXED,
                             __HIP_MEMORY_SCOPE_AGENT) < (unsigned)SS) {
      __builtin_amdgcn_s_sleep(2);
    }
  }
  __syncthreads();
  asm volatile("" ::: "memory");

  phase2_stats(ws, b, tid, sm, scnt, stot);
  phase3_work(emb, lab, ws, b, bxl, tid, sm, scnt, red2);

  if (tid == 0) {
    asm volatile("s_waitcnt vmcnt(0)" ::: "memory");  // drain iacc add
    unsigned* c2s = reinterpret_cast<unsigned*>(
        ws + C2S_OFF + ((size_t)b * SS + (bxl & (SS - 1))) * LINE);
    const unsigned olds = atomicAdd(c2s, 1u);
    unsigned lf = 0u;
    if (olds == (unsigned)(GPB / SS - 1)) {
      asm volatile("s_waitcnt vmcnt(0)" ::: "memory");
      unsigned* gc = reinterpret_cast<unsigned*>(ws + GC_OFF);
      const unsigned oldg = atomicAdd(gc, 1u);
      lf = (oldg == (unsigned)(B * SS - 1)) ? 1u : 0u;
    }
    lastFlag = lf;
  }
  __syncthreads();
  if (!lastFlag) return;

  __shared__ float stF[B * 25];
  __shared__ float sb[B];
  finalize_work(ws, out, tid, stF, sb);
}

// ---- Fallback two-kernel path (identical math & slots -> identical bits;
//      no co-residency requirement, no spin) ----
__global__ __launch_bounds__(NT, 8) void fb_pass1(const float* __restrict__ emb,
                                                  const int* __restrict__ lab,
                                                  float* __restrict__ ws) {
  __shared__ float red[4][25];
  phase1_work(emb, lab, ws, blockIdx.x >> 8, blockIdx.x & (GPB - 1),
              threadIdx.x, red);
}

__global__ __launch_bounds__(NT, 8) void fb_pass23(
    const float* __restrict__ emb, const int* __restrict__ lab,
    float* __restrict__ ws, float* __restrict__ out) {
  const int b = blockIdx.x >> 8, bxl = blockIdx.x & (GPB - 1);
  const int tid = threadIdx.x;
  __shared__ float stot[25];
  __shared__ float sm[K][C];
  __shared__ float scnt[K];
  __shared__ float red2[4][K];
  __shared__ unsigned lastFlag;

  phase2_stats(ws, b, tid, sm, scnt, stot);
  phase3_work(emb, lab, ws, b, bxl, tid, sm, scnt, red2);

  if (tid == 0) {
    asm volatile("s_waitcnt vmcnt(0)" ::: "memory");
    unsigned* c2s = reinterpret_cast<unsigned*>(
        ws + C2S_OFF + ((size_t)b * SS + (bxl & (SS - 1))) * LINE);
    const unsigned olds = atomicAdd(c2s, 1u);
    unsigned lf = 0u;
    if (olds == (unsigned)(GPB / SS - 1)) {
      asm volatile("s_waitcnt vmcnt(0)" ::: "memory");
      unsigned* gc = reinterpret_cast<unsigned*>(ws + GC_OFF);
      const unsigned oldg = atomicAdd(gc, 1u);
      lf = (oldg == (unsigned)(B * SS - 1)) ? 1u : 0u;
    }
    lastFlag = lf;
  }
  __syncthreads();
  if (!lastFlag) return;

  __shared__ float stF[B * 25];
  __shared__ float sb[B];
  finalize_work(ws, out, tid, stF, sb);
}

}  // namespace

extern "C" void kernel_launch(void* const* d_in, const int* in_sizes, int n_in,
                              void* d_out, int out_size, void* d_ws,
                              size_t ws_size, hipStream_t stream) {
  const float* emb = (const float*)d_in[0];
  const int* lab = (const int*)d_in[1];
  float* out = (float*)d_out;
  float* ws = (float*)d_ws;

  // Capture-safe, deterministic occupancy query: fused path only if 8
  // blocks/CU are guaranteed co-resident (256 CUs * 8 = 2048 = NBLK).
  int blocksPerCU = 0;
  const hipError_t qerr = hipOccupancyMaxActiveBlocksPerMultiprocessor(
      &blocksPerCU, fused_kernel, NT, 0);
  const bool coop_ok = (qerr == hipSuccess) && (blocksPerCU >= 8);

  zero_kernel<<<(WS_FLOATS + NT - 1) / NT, NT, 0, stream>>>(ws);
  if (coop_ok) {
    fused_kernel<<<NBLK, NT, 0, stream>>>(emb, lab, ws, out);
  } else {
    fb_pass1<<<NBLK, NT, 0, stream>>>(emb, lab, ws);
    fb_pass23<<<NBLK, NT, 0, stream>>>(emb, lab, ws, out);
  }
}

// Round 12
// 61.756 us; speedup vs baseline: 1.0748x; 1.0748x over previous
//
#include <hip/hip_runtime.h>

namespace {

constexpr int B = 8, C = 4, K = 5;
constexpr int HW = 512 * 1024;  // pixels per (b,c) plane
constexpr int NG = HW / 4;      // float4 groups per plane (131072)
constexpr int NT = 256;         // threads per block
constexpr int GPB = 256;        // blocks per batch
constexpr int NBLK = GPB * B;   // 2048 blocks
constexpr int SGRP = GPB * NT;  // 65536 = NG/2 -> exactly 2 groups/thread
constexpr int SS = 4;           // atomic sub-slots (64-long RMW chains)
constexpr int LINE = 32;        // floats per 128B line
constexpr float DV = 0.5f;      // DELTA_V
constexpr float DD = 3.0f;      // DELTA_D
constexpr double FXST = 16777216.0;       // 2^24 stats fixed-point scale
constexpr double FXSV = 1099511627776.0;  // 2^40 var fixed-point scale

using u64 = unsigned long long;

// ws float layout; every RMW slot owns a 128B line; atomic slots zeroed by
// zero_kernel (node 0) each call. Cross-block sums are INTEGER fixed-point
// (associative -> deterministic). stats[] is written by p1's elected
// batch-last block (plain stores) and read in p2 across the dispatch
// boundary (proven-safe mechanism, same as R5/R9's p1t).
constexpr int ST_OFF = 0;                              // [B*25*SS] u64
constexpr int IACC_OFF = ST_OFF + B * 25 * SS * LINE;  // [B*SS] u64
constexpr int C1S_OFF = IACC_OFF + B * SS * LINE;      // [B*SS] u32
constexpr int C1M_OFF = C1S_OFF + B * SS * LINE;       // [B] u32
constexpr int C2S_OFF = C1M_OFF + B * LINE;            // [B*SS] u32
constexpr int GC_OFF = C2S_OFF + B * SS * LINE;        // 1 u32
constexpr int STAT_OFF = GC_OFF + LINE;                // [B][25] plain floats
constexpr int WS_FLOATS = STAT_OFF + B * LINE;         // 29216 (~117 KB)

__device__ __forceinline__ float wave_reduce(float v) {
#pragma unroll
  for (int m = 32; m; m >>= 1) v += __shfl_xor(v, m, 64);
  return v;
}

__device__ __forceinline__ u64 aload64(const float* p) {
  return __hip_atomic_load(reinterpret_cast<const u64*>(p), __ATOMIC_RELAXED,
                           __HIP_MEMORY_SCOPE_AGENT);
}

__global__ void zero_kernel(float* __restrict__ ws) {
  const int i = blockIdx.x * blockDim.x + threadIdx.x;
  if (i < WS_FLOATS) ws[i] = 0.f;
}

// ---- Pass 1: label counts + channel sums -> ST atomic slots; elected
//      batch-last block reduces slots -> plain stats[b][25] (means+counts) --
__global__ __launch_bounds__(NT, 8) void p1_kernel(
    const float* __restrict__ emb, const int* __restrict__ lab,
    float* __restrict__ ws) {
  const int b = blockIdx.x >> 8, bxl = blockIdx.x & (GPB - 1);
  const int tid = threadIdx.x, wv = tid >> 6, ln = tid & 63;
  const float4* __restrict__ ep =
      reinterpret_cast<const float4*>(emb + (size_t)b * C * HW);
  const int4* __restrict__ lp =
      reinterpret_cast<const int4*>(lab + (size_t)b * HW);
  const int g0 = bxl * NT + tid, g1 = g0 + SGRP;

  const int4 la = lp[g0], lb2 = lp[g1];
  const float4 a0 = ep[g0], a1 = ep[NG + g0], a2 = ep[2 * NG + g0],
               a3 = ep[3 * NG + g0];
  const float4 b0 = ep[g1], b1 = ep[NG + g1], b2 = ep[2 * NG + g1],
               b3 = ep[3 * NG + g1];

  float acc[25];  // [k][{c0..c3,cnt}] flat, compile-time indexed only
#pragma unroll
  for (int i = 0; i < 25; i++) acc[i] = 0.f;
  auto accum = [&](int l, float v0, float v1, float v2, float v3) {
#pragma unroll
    for (int k = 0; k < K; k++) {  // branchless predicated accumulate
      const float m = (l == k + 1) ? 1.f : 0.f;
      acc[k * 5 + 0] = fmaf(m, v0, acc[k * 5 + 0]);
      acc[k * 5 + 1] = fmaf(m, v1, acc[k * 5 + 1]);
      acc[k * 5 + 2] = fmaf(m, v2, acc[k * 5 + 2]);
      acc[k * 5 + 3] = fmaf(m, v3, acc[k * 5 + 3]);
      acc[k * 5 + 4] += m;
    }
  };
  accum(la.x, a0.x, a1.x, a2.x, a3.x);
  accum(la.y, a0.y, a1.y, a2.y, a3.y);
  accum(la.z, a0.z, a1.z, a2.z, a3.z);
  accum(la.w, a0.w, a1.w, a2.w, a3.w);
  accum(lb2.x, b0.x, b1.x, b2.x, b3.x);
  accum(lb2.y, b0.y, b1.y, b2.y, b3.y);
  accum(lb2.z, b0.z, b1.z, b2.z, b3.z);
  accum(lb2.w, b0.w, b1.w, b2.w, b3.w);

  __shared__ float red[4][25];
#pragma unroll
  for (int i = 0; i < 25; i++) {
    const float v = wave_reduce(acc[i]);
    if (ln == 0) red[wv][i] = v;
  }
  __syncthreads();
  if (tid < 25) {  // publish: integer atomicAdd, 64-long chain per sub-slot
    const float t =
        (red[0][tid] + red[1][tid]) + (red[2][tid] + red[3][tid]);
    const long long q = (long long)((double)t * FXST);
    atomicAdd(reinterpret_cast<u64*>(
                  ws + ST_OFF +
                  ((size_t)(b * 25 + tid) * SS + (bxl & (SS - 1))) * LINE),
              (u64)q);
  }

  // elect the batch-last block (two-level counters, each post-vmcnt)
  __shared__ unsigned lastFlag;
  if (tid == 0) {
    asm volatile("s_waitcnt vmcnt(0)" ::: "memory");  // drain publishes
    unsigned* c1s = reinterpret_cast<unsigned*>(
        ws + C1S_OFF + ((size_t)b * SS + (bxl & (SS - 1))) * LINE);
    const unsigned olds = atomicAdd(c1s, 1u);
    unsigned lf = 0u;
    if (olds == (unsigned)(GPB / SS - 1)) {  // sub-group finisher
      asm volatile("s_waitcnt vmcnt(0)" ::: "memory");
      unsigned* c1m =
          reinterpret_cast<unsigned*>(ws + C1M_OFF + (size_t)b * LINE);
      const unsigned oldm = atomicAdd(c1m, 1u);
      lf = (oldm == (unsigned)(SS - 1)) ? 1u : 0u;
    }
    lastFlag = lf;
  }
  __syncthreads();
  if (!lastFlag) return;

  // batch-last block: reduce ST slots -> means + count, plain-store stats
  if (tid < 25) {
    long long s = 0;
#pragma unroll
    for (int j = 0; j < SS; j++)
      s += (long long)aload64(ws + ST_OFF +
                              ((size_t)(b * 25 + tid) * SS + j) * LINE);
    const float t = (float)((double)s / FXST);
    __shared__ float stot[25];
    stot[tid] = t;
    __builtin_amdgcn_s_barrier();  // 25 active lanes, same wave-ish; cheap
    const float cnt = stot[(tid / 5) * 5 + 4];
    ws[STAT_OFF + b * LINE + tid] = (tid % 5 == 4) ? cnt : stot[tid] / cnt;
  }
}

// ---- Pass 2: plain-load stats -> masked relu(||e-mean||-DV)^2 -> iacc
//      atomics -> elected global-last block finalizes -> out ----
__global__ __launch_bounds__(NT, 8) void p2_kernel(
    const float* __restrict__ emb, const int* __restrict__ lab,
    float* __restrict__ ws, float* __restrict__ out) {
  const int b = blockIdx.x >> 8, bxl = blockIdx.x & (GPB - 1);
  const int tid = threadIdx.x, wv = tid >> 6, ln = tid & 63;

  __shared__ float stot[25];
  if (tid < 25) stot[tid] = ws[STAT_OFF + b * LINE + tid];  // plain, L2-hit
  __syncthreads();
  __shared__ float sm[K][C];
  __shared__ float scnt[K];
  if (tid < K * C) {
    const int k = tid / C, c = tid % C;
    sm[k][c] = stot[k * 5 + c];  // already means
  }
  if (tid < K) scnt[tid] = stot[tid * 5 + 4];
  __syncthreads();

  const float4* __restrict__ ep =
      reinterpret_cast<const float4*>(emb + (size_t)b * C * HW);
  const int4* __restrict__ lp =
      reinterpret_cast<const int4*>(lab + (size_t)b * HW);
  const int g0 = bxl * NT + tid, g1 = g0 + SGRP;

  const int4 la = lp[g0], lb2 = lp[g1];
  const float4 a0 = ep[g0], a1 = ep[NG + g0], a2 = ep[2 * NG + g0],
               a3 = ep[3 * NG + g0];
  const float4 b0 = ep[g1], b1 = ep[NG + g1], b2 = ep[2 * NG + g1],
               b3 = ep[3 * NG + g1];

  float vacc[K] = {0.f, 0.f, 0.f, 0.f, 0.f};
  auto accum = [&](int l, float v0, float v1, float v2, float v3) {
    const int kk = (l > 0) ? (l - 1) : 0;  // safe index; l==0 masked below
    const float d0 = v0 - sm[kk][0];
    const float d1 = v1 - sm[kk][1];
    const float d2 = v2 - sm[kk][2];
    const float d3 = v3 - sm[kk][3];
    const float t =
        fmaxf(sqrtf(d0 * d0 + d1 * d1 + d2 * d2 + d3 * d3) - DV, 0.f);
    const float t2 = t * t;
#pragma unroll
    for (int k = 0; k < K; k++) vacc[k] += (l == k + 1) ? t2 : 0.f;
  };
  accum(la.x, a0.x, a1.x, a2.x, a3.x);
  accum(la.y, a0.y, a1.y, a2.y, a3.y);
  accum(la.z, a0.z, a1.z, a2.z, a3.z);
  accum(la.w, a0.w, a1.w, a2.w, a3.w);
  accum(lb2.x, b0.x, b1.x, b2.x, b3.x);
  accum(lb2.y, b0.y, b1.y, b2.y, b3.y);
  accum(lb2.z, b0.z, b1.z, b2.z, b3.z);
  accum(lb2.w, b0.w, b1.w, b2.w, b3.w);

  __shared__ float red2[4][K];
#pragma unroll
  for (int i = 0; i < K; i++) {
    const float v = wave_reduce(vacc[i]);
    if (ln == 0) red2[wv][i] = v;
  }
  __syncthreads();

  __shared__ unsigned lastFlag;
  if (tid == 0) {
    float sblk = 0.f;
#pragma unroll
    for (int k = 0; k < K; k++) {
      sblk += ((red2[0][k] + red2[1][k]) + (red2[2][k] + red2[3][k])) /
              scnt[k];
    }
    const u64 fx = (u64)(long long)((double)sblk * FXSV);
    atomicAdd(reinterpret_cast<u64*>(
                  ws + IACC_OFF + ((size_t)b * SS + (bxl & (SS - 1))) * LINE),
              fx);
    asm volatile("s_waitcnt vmcnt(0)" ::: "memory");
    unsigned* c2s = reinterpret_cast<unsigned*>(
        ws + C2S_OFF + ((size_t)b * SS + (bxl & (SS - 1))) * LINE);
    const unsigned olds = atomicAdd(c2s, 1u);
    unsigned lf = 0u;
    if (olds == (unsigned)(GPB / SS - 1)) {
      asm volatile("s_waitcnt vmcnt(0)" ::: "memory");
      unsigned* gc = reinterpret_cast<unsigned*>(ws + GC_OFF);
      const unsigned oldg = atomicAdd(gc, 1u);
      lf = (oldg == (unsigned)(B * SS - 1)) ? 1u : 0u;
    }
    lastFlag = lf;
  }
  __syncthreads();
  if (!lastFlag) return;

  // finalize: stats via plain loads (p1 data), iacc via atomic loads
  __shared__ float stF[B * 25];
  if (tid < B * 25)
    stF[tid] = ws[STAT_OFF + (tid / 25) * LINE + (tid % 25)];
  __shared__ float sb[B];
  if (tid < B) {
    long long s = 0;
#pragma unroll
    for (int j = 0; j < SS; j++)
      s += (long long)aload64(ws + IACC_OFF + ((size_t)tid * SS + j) * LINE);
    sb[tid] = (float)((double)s / FXSV);
  }
  __syncthreads();
  if (tid != 0) return;

  float v = 0.f, d = 0.f;
  for (int bb = 0; bb < B; bb++) {
    float m[K][C];  // stF already holds means (count at slot 4)
#pragma unroll
    for (int k = 0; k < K; k++) {
#pragma unroll
      for (int c = 0; c < C; c++) m[k][c] = stF[bb * 25 + k * 5 + c];
    }
    float p = 0.f;
#pragma unroll
    for (int i = 0; i < K; i++) {
#pragma unroll
      for (int j = 0; j < K; j++) {
        if (i == j) continue;  // diagonal term is exactly 0
        float dd = 0.f;
#pragma unroll
        for (int c = 0; c < C; c++) {
          const float t = m[i][c] - m[j][c];
          dd += t * t;
        }
        const float r = fmaxf(DD - sqrtf(dd), 0.f);
        p += r * r;
      }
    }
    v = (v + sb[bb]) / (float)K;
    d = (d + p) / (float)(2 * K * (K - 1));
  }
  out[0] = v / (float)B;
  out[1] = d / (float)B;
}

}  // namespace

extern "C" void kernel_launch(void* const* d_in, const int* in_sizes, int n_in,
                              void* d_out, int out_size, void* d_ws,
                              size_t ws_size, hipStream_t stream) {
  const float* emb = (const float*)d_in[0];
  const int* lab = (const int*)d_in[1];
  float* out = (float*)d_out;
  float* ws = (float*)d_ws;

  zero_kernel<<<(WS_FLOATS + NT - 1) / NT, NT, 0, stream>>>(ws);
  p1_kernel<<<NBLK, NT, 0, stream>>>(emb, lab, ws);
  p2_kernel<<<NBLK, NT, 0, stream>>>(emb, lab, ws, out);
}

// Round 13
// 53.917 us; speedup vs baseline: 1.2311x; 1.1454x over previous
//
#include <hip/hip_runtime.h>

namespace {

constexpr int B = 8, C = 4, K = 5;
constexpr int HW = 512 * 1024;     // pixels per (b,c) plane
constexpr int NG = HW / 4;         // float4 groups per plane (131072)
constexpr int NT = 256;            // threads per block
constexpr int GPB = 128;           // blocks per batch
constexpr int NBLK = GPB * B;      // 1024 blocks = 4/CU (LDS-limited) -> co-resident
constexpr int GRP_BLK = NG / GPB;  // 1024 groups (4096 pixels) per block
constexpr int IT = GRP_BLK / NT;   // 4 iterations of 1 group/thread
constexpr int SS = 2;              // atomic sub-slots (64-long RMW chains)
constexpr int LINE = 32;           // floats per 128B line
constexpr float DV = 0.5f;         // DELTA_V
constexpr float DD = 3.0f;         // DELTA_D
constexpr double FXST = 16777216.0;       // 2^24 stats fixed-point scale
constexpr double FXSV = 1099511627776.0;  // 2^40 var fixed-point scale

using u64 = unsigned long long;

// ws layout; every RMW slot owns a 128B line; all zeroed by zero_kernel
// (node 0). All cross-block sums are INTEGER fixed-point (associative ->
// deterministic). Proven R10/R11 machinery.
constexpr int ST_OFF = 0;                              // [B*25*SS] u64
constexpr int IACC_OFF = ST_OFF + B * 25 * SS * LINE;  // [B*SS] u64
constexpr int C1S_OFF = IACC_OFF + B * SS * LINE;      // [B*SS] u32
constexpr int C1M_OFF = C1S_OFF + B * SS * LINE;       // [B] u32
constexpr int C2S_OFF = C1M_OFF + B * LINE;            // [B*SS] u32
constexpr int GC_OFF = C2S_OFF + B * SS * LINE;        // 1 u32
constexpr int WS_FLOATS = GC_OFF + LINE;               // ~14.7K floats

__device__ __forceinline__ float wave_reduce(float v) {
#pragma unroll
  for (int m = 32; m; m >>= 1) v += __shfl_xor(v, m, 64);
  return v;
}

__device__ __forceinline__ u64 aload64(const float* p) {
  return __hip_atomic_load(reinterpret_cast<const u64*>(p), __ATOMIC_RELAXED,
                           __HIP_MEMORY_SCOPE_AGENT);
}

// bf16 pack (round-to-nearest-even: no systematic bias) / unpack
__device__ __forceinline__ unsigned rtne16(float x) {
  const unsigned u = __float_as_uint(x);
  return u + 0x7fffu + ((u >> 16) & 1u);
}
__device__ __forceinline__ unsigned pk(float lo, float hi) {
  return (rtne16(lo) >> 16) | (rtne16(hi) & 0xffff0000u);
}
__device__ __forceinline__ float bflo(unsigned p) {
  return __uint_as_float(p << 16);
}
__device__ __forceinline__ float bfhi(unsigned p) {
  return __uint_as_float(p & 0xffff0000u);
}

__global__ void zero_kernel(float* __restrict__ ws) {
  const int i = blockIdx.x * blockDim.x + threadIdx.x;
  if (i < WS_FLOATS) ws[i] = 0.f;
}

// Fused: phase1 streams HBM once (fp32 stats accumulate + bf16 LDS cache)
// -> per-batch spin barrier -> phase3 re-reads pixels from LDS only.
__global__ __launch_bounds__(NT, 4) void fused_kernel(
    const float* __restrict__ emb, const int* __restrict__ lab,
    float* __restrict__ ws, float* __restrict__ out) {
  const int b = blockIdx.x >> 7, bxl = blockIdx.x & (GPB - 1);
  const int tid = threadIdx.x, wv = tid >> 6, ln = tid & 63;

  __shared__ unsigned e01[GRP_BLK * 4];  // 16 KB: pixel -> bf16(c0,c1)
  __shared__ unsigned e23[GRP_BLK * 4];  // 16 KB: pixel -> bf16(c2,c3)
  __shared__ unsigned labp[GRP_BLK];     //  4 KB: 4 labels/u32
  __shared__ float red[4][25];
  __shared__ float stot[25];
  __shared__ float sm[K][C];
  __shared__ float scnt[K];
  __shared__ float red2[4][K];
  __shared__ unsigned lastFlag;

  const float4* __restrict__ ep =
      reinterpret_cast<const float4*>(emb + (size_t)b * C * HW);
  const int4* __restrict__ lp =
      reinterpret_cast<const int4*>(lab + (size_t)b * HW);

  // ---------------- Phase 1: single HBM sweep ----------------
  float acc[25];  // [k][{c0..c3,cnt}] flat, compile-time indexed only
#pragma unroll
  for (int i = 0; i < 25; i++) acc[i] = 0.f;
  auto accum1 = [&](int l, float v0, float v1, float v2, float v3) {
#pragma unroll
    for (int k = 0; k < K; k++) {  // branchless predicated accumulate
      const float m = (l == k + 1) ? 1.f : 0.f;
      acc[k * 5 + 0] = fmaf(m, v0, acc[k * 5 + 0]);
      acc[k * 5 + 1] = fmaf(m, v1, acc[k * 5 + 1]);
      acc[k * 5 + 2] = fmaf(m, v2, acc[k * 5 + 2]);
      acc[k * 5 + 3] = fmaf(m, v3, acc[k * 5 + 3]);
      acc[k * 5 + 4] += m;
    }
  };

#pragma unroll 1
  for (int it = 0; it < IT; it++) {
    const int lg = it * NT + tid;            // local group (coalesced/iter)
    const int g = bxl * GRP_BLK + lg;        // group within batch
    const int4 la = lp[g];
    const float4 e0 = ep[g], e1 = ep[NG + g], e2 = ep[2 * NG + g],
                 e3 = ep[3 * NG + g];
    // fp32-exact stats accumulate
    accum1(la.x, e0.x, e1.x, e2.x, e3.x);
    accum1(la.y, e0.y, e1.y, e2.y, e3.y);
    accum1(la.z, e0.z, e1.z, e2.z, e3.z);
    accum1(la.w, e0.w, e1.w, e2.w, e3.w);
    // cache pixels to LDS as bf16 pairs + packed labels
    uint4 w01, w23;
    w01.x = pk(e0.x, e1.x); w23.x = pk(e2.x, e3.x);
    w01.y = pk(e0.y, e1.y); w23.y = pk(e2.y, e3.y);
    w01.z = pk(e0.z, e1.z); w23.z = pk(e2.z, e3.z);
    w01.w = pk(e0.w, e1.w); w23.w = pk(e2.w, e3.w);
    *reinterpret_cast<uint4*>(&e01[lg * 4]) = w01;
    *reinterpret_cast<uint4*>(&e23[lg * 4]) = w23;
    labp[lg] = (unsigned)(la.x & 0xff) | ((unsigned)(la.y & 0xff) << 8) |
               ((unsigned)(la.z & 0xff) << 16) |
               ((unsigned)(la.w & 0xff) << 24);
  }

#pragma unroll
  for (int i = 0; i < 25; i++) {
    const float v = wave_reduce(acc[i]);
    if (ln == 0) red[wv][i] = v;
  }
  __syncthreads();
  if (tid < 25) {  // publish stats: integer atomicAdd, 64-long chains
    const float t =
        (red[0][tid] + red[1][tid]) + (red[2][tid] + red[3][tid]);
    const long long q = (long long)((double)t * FXST);
    atomicAdd(reinterpret_cast<u64*>(
                  ws + ST_OFF +
                  ((size_t)(b * 25 + tid) * SS + (bxl & (SS - 1))) * LINE),
              (u64)q);
  }

  // per-batch barrier: two-level arrival + relaxed spin (R10/R11-proven)
  if (tid == 0) {
    asm volatile("s_waitcnt vmcnt(0)" ::: "memory");  // drain publishes
    unsigned* c1s = reinterpret_cast<unsigned*>(
        ws + C1S_OFF + ((size_t)b * SS + (bxl & (SS - 1))) * LINE);
    const unsigned olds = atomicAdd(c1s, 1u);
    if (olds == (unsigned)(GPB / SS - 1)) {  // sub-group finisher
      asm volatile("s_waitcnt vmcnt(0)" ::: "memory");
      atomicAdd(reinterpret_cast<unsigned*>(ws + C1M_OFF + (size_t)b * LINE),
                1u);
    }
    const unsigned* c1m =
        reinterpret_cast<const unsigned*>(ws + C1M_OFF + (size_t)b * LINE);
    while (__hip_atomic_load(c1m, __ATOMIC_RELAXED,
                             __HIP_MEMORY_SCOPE_AGENT) < (unsigned)SS) {
      __builtin_amdgcn_s_sleep(2);
    }
  }
  __syncthreads();
  asm volatile("" ::: "memory");

  // ---------------- Phase 2: read batch stats -> means ----------------
  if (tid < 25) {
    long long s = 0;
#pragma unroll
    for (int j = 0; j < SS; j++)
      s += (long long)aload64(ws + ST_OFF +
                              ((size_t)(b * 25 + tid) * SS + j) * LINE);
    stot[tid] = (float)((double)s / FXST);
  }
  __syncthreads();
  if (tid < K * C) {
    const int k = tid / C, c = tid % C;
    sm[k][c] = stot[k * 5 + c] / stot[k * 5 + 4];
  }
  if (tid < K) scnt[tid] = stot[tid * 5 + 4];
  __syncthreads();

  // ---------------- Phase 3: LDS-only sweep ----------------
  float vacc[K] = {0.f, 0.f, 0.f, 0.f, 0.f};
  auto accum2 = [&](int l, float v0, float v1, float v2, float v3) {
    const int kk = (l > 0) ? (l - 1) : 0;  // safe index; l==0 masked below
    const float d0 = v0 - sm[kk][0];
    const float d1 = v1 - sm[kk][1];
    const float d2 = v2 - sm[kk][2];
    const float d3 = v3 - sm[kk][3];
    const float t =
        fmaxf(sqrtf(d0 * d0 + d1 * d1 + d2 * d2 + d3 * d3) - DV, 0.f);
    const float t2 = t * t;
#pragma unroll
    for (int k = 0; k < K; k++) vacc[k] += (l == k + 1) ? t2 : 0.f;
  };
#pragma unroll 1
  for (int it = 0; it < IT; it++) {
    const int lg = it * NT + tid;
    const uint4 r01 = *reinterpret_cast<const uint4*>(&e01[lg * 4]);
    const uint4 r23 = *reinterpret_cast<const uint4*>(&e23[lg * 4]);
    const unsigned lw = labp[lg];
    accum2((int)(lw & 0xffu), bflo(r01.x), bfhi(r01.x), bflo(r23.x),
           bfhi(r23.x));
    accum2((int)((lw >> 8) & 0xffu), bflo(r01.y), bfhi(r01.y), bflo(r23.y),
           bfhi(r23.y));
    accum2((int)((lw >> 16) & 0xffu), bflo(r01.z), bfhi(r01.z), bflo(r23.z),
           bfhi(r23.z));
    accum2((int)((lw >> 24) & 0xffu), bflo(r01.w), bfhi(r01.w), bflo(r23.w),
           bfhi(r23.w));
  }

#pragma unroll
  for (int i = 0; i < K; i++) {
    const float v = wave_reduce(vacc[i]);
    if (ln == 0) red2[wv][i] = v;
  }
  __syncthreads();

  if (tid == 0) {
    float sblk = 0.f;
#pragma unroll
    for (int k = 0; k < K; k++) {
      sblk += ((red2[0][k] + red2[1][k]) + (red2[2][k] + red2[3][k])) /
              scnt[k];
    }
    const u64 fx = (u64)(long long)((double)sblk * FXSV);
    atomicAdd(reinterpret_cast<u64*>(
                  ws + IACC_OFF + ((size_t)b * SS + (bxl & (SS - 1))) * LINE),
              fx);
    asm volatile("s_waitcnt vmcnt(0)" ::: "memory");
    unsigned* c2s = reinterpret_cast<unsigned*>(
        ws + C2S_OFF + ((size_t)b * SS + (bxl & (SS - 1))) * LINE);
    const unsigned olds = atomicAdd(c2s, 1u);
    unsigned lf = 0u;
    if (olds == (unsigned)(GPB / SS - 1)) {
      asm volatile("s_waitcnt vmcnt(0)" ::: "memory");
      unsigned* gc = reinterpret_cast<unsigned*>(ws + GC_OFF);
      const unsigned oldg = atomicAdd(gc, 1u);
      lf = (oldg == (unsigned)(B * SS - 1)) ? 1u : 0u;
    }
    lastFlag = lf;
  }
  __syncthreads();
  if (!lastFlag) return;

  // ---------------- Finalize (unique global-last block) ----------------
  __shared__ float stF[B * 25];
  __shared__ float sb[B];
  if (tid < B * 25) {
    long long s = 0;
#pragma unroll
    for (int j = 0; j < SS; j++)
      s += (long long)aload64(ws + ST_OFF + ((size_t)tid * SS + j) * LINE);
    stF[tid] = (float)((double)s / FXST);
  }
  if (tid < B) {
    long long s = 0;
#pragma unroll
    for (int j = 0; j < SS; j++)
      s += (long long)aload64(ws + IACC_OFF + ((size_t)tid * SS + j) * LINE);
    sb[tid] = (float)((double)s / FXSV);
  }
  __syncthreads();
  if (tid != 0) return;

  float v = 0.f, d = 0.f;
  for (int bb = 0; bb < B; bb++) {
    float m[K][C];
#pragma unroll
    for (int k = 0; k < K; k++) {
      const float cnt = stF[bb * 25 + k * 5 + 4];
#pragma unroll
      for (int c = 0; c < C; c++) m[k][c] = stF[bb * 25 + k * 5 + c] / cnt;
    }
    float p = 0.f;
#pragma unroll
    for (int i = 0; i < K; i++) {
#pragma unroll
      for (int j = 0; j < K; j++) {
        if (i == j) continue;  // diagonal term is exactly 0
        float dd = 0.f;
#pragma unroll
        for (int c = 0; c < C; c++) {
          const float t = m[i][c] - m[j][c];
          dd += t * t;
        }
        const float r = fmaxf(DD - sqrtf(dd), 0.f);
        p += r * r;
      }
    }
    v = (v + sb[bb]) / (float)K;
    d = (d + p) / (float)(2 * K * (K - 1));
  }
  out[0] = v / (float)B;
  out[1] = d / (float)B;
}

}  // namespace

extern "C" void kernel_launch(void* const* d_in, const int* in_sizes, int n_in,
                              void* d_out, int out_size, void* d_ws,
                              size_t ws_size, hipStream_t stream) {
  const float* emb = (const float*)d_in[0];
  const int* lab = (const int*)d_in[1];
  float* out = (float*)d_out;
  float* ws = (float*)d_ws;

  zero_kernel<<<(WS_FLOATS + NT - 1) / NT, NT, 0, stream>>>(ws);
  fused_kernel<<<NBLK, NT, 0, stream>>>(emb, lab, ws, out);
}